// Round 3
// baseline (1613.888 us; speedup 1.0000x reference)
//
#include <hip/hip_runtime.h>
#include <hip/hip_bf16.h>
#include <cstdint>
#include <cstddef>

#define N_TOKENS  4096
#define DIM       2048
#define N_EXPERTS 32
#define TOPK      4
#define INTER     1408
#define TWO_INTER 2816
#define CAP       1024
#define T_ASSIGN  (N_TOKENS*TOPK)

typedef __attribute__((ext_vector_type(8))) short short8;
typedef __attribute__((ext_vector_type(4))) float f32x4;

__device__ __forceinline__ unsigned pack_bf16(float a, float b) {
  unsigned ua = __builtin_bit_cast(unsigned, a);
  unsigned ub = __builtin_bit_cast(unsigned, b);
  ua = (ua + 0x8000u) >> 16;
  ub = (ub + 0x8000u) & 0xFFFF0000u;
  return ua | ub;
}
__device__ __forceinline__ unsigned short bf16_1(float a) {
  return (unsigned short)((__builtin_bit_cast(unsigned, a) + 0x8000u) >> 16);
}

// async global(per-lane addr) -> LDS(linear, wave-uniform base + lane*16)
__device__ __forceinline__ void gl_lds16(const void* g, void* l) {
  __builtin_amdgcn_global_load_lds(
      (const __attribute__((address_space(1))) unsigned int*)g,
      (__attribute__((address_space(3))) unsigned int*)l, 16, 0, 0);
}

// ---------------- routing build ----------------
__global__ void k_build(const int* __restrict__ tmask, const float* __restrict__ w,
                        const int* __restrict__ idx, int* __restrict__ counts,
                        int* __restrict__ tok, float* __restrict__ pb) {
  int i = blockIdx.x * 256 + threadIdx.x;
  if (i >= T_ASSIGN) return;
  int t = i >> 2;
  int e = idx[i];
  if (e < 0 || e >= N_EXPERTS) return;
  if (tmask[t] == 0) return;
  int r = atomicAdd(&counts[e], 1);
  if (r < CAP) {
    tok[e * CAP + r] = t;
    pb[e * CAP + r] = w[i];
  }
}

// ---------------- fp32 -> bf16 linear convert ----------------
__global__ __launch_bounds__(256) void k_conv(const float* __restrict__ src,
                                              __hip_bfloat16* __restrict__ dst, int n4) {
  int i = blockIdx.x * 256 + threadIdx.x;
  int stride = gridDim.x * 256;
  for (; i < n4; i += stride) {
    float4 v = *(const float4*)(src + (size_t)i * 4);
    *(uint2*)(dst + (size_t)i * 4) = make_uint2(pack_bf16(v.x, v.y), pack_bf16(v.z, v.w));
  }
}

// ---------------- fp32 [E][R][C] -> bf16 [E][C][R] transpose-convert ----------------
__global__ __launch_bounds__(256) void k_tconv(const float* __restrict__ src,
                                               __hip_bfloat16* __restrict__ dst,
                                               int R, int C) {
  __shared__ unsigned short s[64][88];
  int nrt = R >> 6, nct = C >> 6;
  int bid = blockIdx.x;
  int e  = bid / (nrt * nct);
  int rr = bid % (nrt * nct);
  int rt = rr / nct, ct = rr % nct;
  int r0 = rt * 64, c0 = ct * 64;
  const float* sp = src + (size_t)e * R * C;
  int t = threadIdx.x;
  int lr  = t >> 4;
  int lc4 = (t & 15) * 4;
  #pragma unroll
  for (int p = 0; p < 4; ++p) {
    int r = lr + p * 16;
    float4 v = *(const float4*)(sp + (size_t)(r0 + r) * C + c0 + lc4);
    s[lc4 + 0][r] = bf16_1(v.x);
    s[lc4 + 1][r] = bf16_1(v.y);
    s[lc4 + 2][r] = bf16_1(v.z);
    s[lc4 + 3][r] = bf16_1(v.w);
  }
  __syncthreads();
  __hip_bfloat16* dp = dst + (size_t)e * C * R;
  int wc   = t >> 2;
  int wr16 = (t & 3) * 16;
  uint4 o0 = *(const uint4*)&s[wc][wr16];
  uint4 o1 = *(const uint4*)&s[wc][wr16 + 8];
  __hip_bfloat16* o = dp + (size_t)(c0 + wc) * R + r0 + wr16;
  *(uint4*)o = o0;
  *(uint4*)(o + 8) = o1;
}

// ================= 256x256-tile grouped GEMMs (2-phase, gl_lds staging) =================

// GEMM1: act[e*CAP+m][h] = GEGLU( gather(xb) @ gupT[e]^T ) * prob
__global__ __launch_bounds__(512, 2) void k_gemm1n(
    const __hip_bfloat16* __restrict__ xb, const __hip_bfloat16* __restrict__ gupT,
    const int* __restrict__ counts, const int* __restrict__ tok,
    const float* __restrict__ pb, __hip_bfloat16* __restrict__ act)
{
  const int MT = CAP / 256;        // 4
  const int NT = TWO_INTER / 256;  // 11
  const int nwg = N_EXPERTS * NT * MT;  // 1408, %8==0
  int bid = (int)((blockIdx.x & 7) * (nwg >> 3) + (blockIdx.x >> 3));
  int e  = bid / (NT * MT);
  int rr = bid % (NT * MT);
  int nt = rr / MT, mt = rr % MT;
  const int cnt = counts[e];
  const int m0 = mt * 256;
  if (m0 >= cnt) return;
  const int n0 = nt * 256;

  __shared__ __hip_bfloat16 As[256 * 64];
  __shared__ __hip_bfloat16 Bs[256 * 64];
  __shared__ int toks[256];

  const int tid = threadIdx.x, lane = tid & 63, w = tid >> 6;  // w 0..7
  const int wr = w >> 2, wc = w & 3;                            // 2M x 4N
  if (tid < 256) toks[tid] = tok[e * CAP + m0 + tid];
  __syncthreads();

  const __hip_bfloat16* gT = gupT + (size_t)e * TWO_INTER * DIM;
  const __hip_bfloat16* ab[4];
  const __hip_bfloat16* bb[4];
  const int kc8 = (lane & 7) * 8;
  #pragma unroll
  for (int i = 0; i < 4; ++i) {
    int row = w * 8 + 64 * i + (lane >> 3);
    ab[i] = xb + (size_t)toks[row] * DIM + kc8;
    bb[i] = gT + (size_t)(n0 + row) * DIM + kc8;
  }

  f32x4 acc[8][4];
  #pragma unroll
  for (int i = 0; i < 8; ++i)
    #pragma unroll
    for (int j = 0; j < 4; ++j) acc[i][j] = (f32x4){0.f, 0.f, 0.f, 0.f};

  for (int kt = 0; kt < DIM / 64; ++kt) {
    const int k0 = kt * 64;
    #pragma unroll
    for (int i = 0; i < 4; ++i) {
      int loff = (w * 64 + 512 * i + lane) * 16;
      gl_lds16(ab[i] + k0, (char*)As + loff);
      gl_lds16(bb[i] + k0, (char*)Bs + loff);
    }
    __syncthreads();
    #pragma unroll
    for (int ks = 0; ks < 2; ++ks) {
      short8 af[8], bf[4];
      const int koff = ks * 64 + (lane >> 4) * 16;
      #pragma unroll
      for (int mi = 0; mi < 8; ++mi)
        af[mi] = *(const short8*)((const char*)As + (wr * 128 + mi * 16 + (lane & 15)) * 128 + koff);
      #pragma unroll
      for (int ni = 0; ni < 4; ++ni)
        bf[ni] = *(const short8*)((const char*)Bs + (wc * 64 + ni * 16 + (lane & 15)) * 128 + koff);
      #pragma unroll
      for (int mi = 0; mi < 8; ++mi)
        #pragma unroll
        for (int ni = 0; ni < 4; ++ni)
          acc[mi][ni] = __builtin_amdgcn_mfma_f32_16x16x32_bf16(af[mi], bf[ni], acc[mi][ni], 0, 0, 0);
    }
    __syncthreads();
  }

  const int colp = lane & 15;
  const int rgrp = lane >> 4;
  #pragma unroll
  for (int mi = 0; mi < 8; ++mi) {
    #pragma unroll
    for (int j = 0; j < 4; ++j) {
      int rowl = wr * 128 + mi * 16 + rgrp * 4 + j;
      float prob = pb[e * CAP + m0 + rowl];
      size_t arow = (size_t)(e * CAP + m0 + rowl) * INTER;
      #pragma unroll
      for (int ni = 0; ni < 4; ++ni) {
        float v = acc[mi][ni][j];
        float other = __shfl_xor(v, 1, 64);
        if ((lane & 1) == 0) {
          float gate = fminf(v, 7.0f);
          float up   = fminf(fmaxf(other, -7.0f), 7.0f);
          float glu  = gate / (1.0f + __expf(-1.702f * gate));
          float a    = glu * (up + 1.0f) * prob;
          int nh = n0 + wc * 64 + ni * 16 + colp;
          act[arow + (nh >> 1)] = __float2bfloat16(a);
        }
      }
    }
  }
}

// GEMM2: out[tok] += act @ downT[e]^T
__global__ __launch_bounds__(512, 2) void k_gemm2n(
    const __hip_bfloat16* __restrict__ act, const __hip_bfloat16* __restrict__ downT,
    const int* __restrict__ counts, const int* __restrict__ tok,
    float* __restrict__ out)
{
  const int MT = CAP / 256;  // 4
  const int NT = DIM / 256;  // 8
  const int nwg = N_EXPERTS * NT * MT;  // 1024
  int bid = (int)((blockIdx.x & 7) * (nwg >> 3) + (blockIdx.x >> 3));
  int e  = bid / (NT * MT);
  int rr = bid % (NT * MT);
  int nt = rr / MT, mt = rr % MT;
  const int cnt = counts[e];
  const int m0 = mt * 256;
  if (m0 >= cnt) return;
  const int n0 = nt * 256;

  __shared__ __hip_bfloat16 As[256 * 64];
  __shared__ __hip_bfloat16 Bs[256 * 64];
  __shared__ int toks2[256];

  const int tid = threadIdx.x, lane = tid & 63, w = tid >> 6;
  const int wr = w >> 2, wc = w & 3;
  if (tid < 256) toks2[tid] = tok[e * CAP + m0 + tid];

  const __hip_bfloat16* dT = downT + (size_t)e * DIM * INTER;
  const __hip_bfloat16* ab[4];
  const __hip_bfloat16* bb[4];
  const int kc8 = (lane & 7) * 8;
  #pragma unroll
  for (int i = 0; i < 4; ++i) {
    int row = w * 8 + 64 * i + (lane >> 3);
    ab[i] = act + (size_t)(e * CAP + m0 + row) * INTER + kc8;
    bb[i] = dT + (size_t)(n0 + row) * INTER + kc8;
  }

  f32x4 acc[8][4];
  #pragma unroll
  for (int i = 0; i < 8; ++i)
    #pragma unroll
    for (int j = 0; j < 4; ++j) acc[i][j] = (f32x4){0.f, 0.f, 0.f, 0.f};

  for (int kt = 0; kt < INTER / 64; ++kt) {
    const int k0 = kt * 64;
    #pragma unroll
    for (int i = 0; i < 4; ++i) {
      int loff = (w * 64 + 512 * i + lane) * 16;
      gl_lds16(ab[i] + k0, (char*)As + loff);
      gl_lds16(bb[i] + k0, (char*)Bs + loff);
    }
    __syncthreads();
    #pragma unroll
    for (int ks = 0; ks < 2; ++ks) {
      short8 af[8], bf[4];
      const int koff = ks * 64 + (lane >> 4) * 16;
      #pragma unroll
      for (int mi = 0; mi < 8; ++mi)
        af[mi] = *(const short8*)((const char*)As + (wr * 128 + mi * 16 + (lane & 15)) * 128 + koff);
      #pragma unroll
      for (int ni = 0; ni < 4; ++ni)
        bf[ni] = *(const short8*)((const char*)Bs + (wc * 64 + ni * 16 + (lane & 15)) * 128 + koff);
      #pragma unroll
      for (int mi = 0; mi < 8; ++mi)
        #pragma unroll
        for (int ni = 0; ni < 4; ++ni)
          acc[mi][ni] = __builtin_amdgcn_mfma_f32_16x16x32_bf16(af[mi], bf[ni], acc[mi][ni], 0, 0, 0);
    }
    __syncthreads();
  }

  const int colp = lane & 15;
  const int rgrp = lane >> 4;
  #pragma unroll
  for (int mi = 0; mi < 8; ++mi) {
    #pragma unroll
    for (int j = 0; j < 4; ++j) {
      int rowl = wr * 128 + mi * 16 + rgrp * 4 + j;
      int t = toks2[rowl];
      float* orow = out + (size_t)t * DIM + n0;
      #pragma unroll
      for (int ni = 0; ni < 4; ++ni)
        atomicAdd(orow + wc * 64 + ni * 16 + colp, acc[mi][ni][j]);
    }
  }
}

// ================= launch =================

extern "C" void kernel_launch(void* const* d_in, const int* in_sizes, int n_in,
                              void* d_out, int out_size, void* d_ws, size_t ws_size,
                              hipStream_t stream) {
  const float* x     = (const float*)d_in[0];
  const int*   tmask = (const int*)d_in[1];
  const float* w     = (const float*)d_in[2];
  const int*   idx   = (const int*)d_in[3];
  const float* gup   = (const float*)d_in[4];
  const float* down  = (const float*)d_in[5];
  float* out = (float*)d_out;

  char* ws = (char*)d_ws;
  const size_t off_tok   = 256;
  const size_t off_pb    = 256 + 131072;
  const size_t off_act   = 256 + 262144;
  const size_t act_bytes = (size_t)N_EXPERTS * CAP * INTER * 2;
  const size_t off_xb    = off_act + act_bytes;
  const size_t xb_bytes  = (size_t)N_TOKENS * DIM * 2;
  const size_t off_gupT  = off_xb + xb_bytes;
  const size_t gupT_b    = (size_t)N_EXPERTS * TWO_INTER * DIM * 2;
  const size_t off_downT = off_gupT + gupT_b;

  int*   counts = (int*)ws;
  int*   tok    = (int*)(ws + off_tok);
  float* pbuf   = (float*)(ws + off_pb);
  __hip_bfloat16* act   = (__hip_bfloat16*)(ws + off_act);
  __hip_bfloat16* xb    = (__hip_bfloat16*)(ws + off_xb);
  __hip_bfloat16* gupT  = (__hip_bfloat16*)(ws + off_gupT);
  __hip_bfloat16* downT = (__hip_bfloat16*)(ws + off_downT);

  hipMemsetAsync(ws, 0, off_act, stream);
  k_build<<<(T_ASSIGN + 255) / 256, 256, 0, stream>>>(tmask, w, idx, counts, tok, pbuf);
  hipMemsetAsync(d_out, 0, (size_t)N_TOKENS * DIM * sizeof(float), stream);

  k_conv<<<2048, 256, 0, stream>>>(x, xb, (N_TOKENS * DIM) / 4);
  k_tconv<<<N_EXPERTS * (DIM / 64) * (TWO_INTER / 64), 256, 0, stream>>>(gup, gupT, DIM, TWO_INTER);
  k_tconv<<<N_EXPERTS * (INTER / 64) * (DIM / 64), 256, 0, stream>>>(down, downT, INTER, DIM);

  k_gemm1n<<<N_EXPERTS * (TWO_INTER / 256) * (CAP / 256), 512, 0, stream>>>(
      xb, gupT, counts, tok, pbuf, act);
  k_gemm2n<<<N_EXPERTS * (DIM / 256) * (CAP / 256), 512, 0, stream>>>(
      act, downT, counts, tok, out);
}

// Round 4
// 1411.413 us; speedup vs baseline: 1.1435x; 1.1435x over previous
//
#include <hip/hip_runtime.h>
#include <hip/hip_bf16.h>
#include <cstdint>
#include <cstddef>

#define N_TOKENS  4096
#define DIM       2048
#define N_EXPERTS 32
#define TOPK      4
#define INTER     1408
#define TWO_INTER 2816
#define CAP       1024
#define T_ASSIGN  (N_TOKENS*TOPK)

typedef __attribute__((ext_vector_type(8))) short short8;
typedef __attribute__((ext_vector_type(4))) float f32x4;

__device__ __forceinline__ unsigned pack_bf16(float a, float b) {
  unsigned ua = __builtin_bit_cast(unsigned, a);
  unsigned ub = __builtin_bit_cast(unsigned, b);
  ua = (ua + 0x8000u) >> 16;
  ub = (ub + 0x8000u) & 0xFFFF0000u;
  return ua | ub;
}
__device__ __forceinline__ unsigned short bf16_1(float a) {
  return (unsigned short)((__builtin_bit_cast(unsigned, a) + 0x8000u) >> 16);
}

// async global(per-lane addr) -> LDS(linear, wave-uniform base + lane*16)
__device__ __forceinline__ void gl_lds16(const void* g, void* l) {
  __builtin_amdgcn_global_load_lds(
      (const __attribute__((address_space(1))) unsigned int*)g,
      (__attribute__((address_space(3))) unsigned int*)l, 16, 0, 0);
}

// ---------------- routing build ----------------
__global__ void k_build(const int* __restrict__ tmask, const float* __restrict__ w,
                        const int* __restrict__ idx, int* __restrict__ counts,
                        int* __restrict__ tok, float* __restrict__ pb) {
  int i = blockIdx.x * 256 + threadIdx.x;
  if (i >= T_ASSIGN) return;
  int t = i >> 2;
  int e = idx[i];
  if (e < 0 || e >= N_EXPERTS) return;
  if (tmask[t] == 0) return;
  int r = atomicAdd(&counts[e], 1);
  if (r < CAP) {
    tok[e * CAP + r] = t;
    pb[e * CAP + r] = w[i];
  }
}

// ---------------- fp32 -> bf16 linear convert ----------------
__global__ __launch_bounds__(256) void k_conv(const float* __restrict__ src,
                                              __hip_bfloat16* __restrict__ dst, int n4) {
  int i = blockIdx.x * 256 + threadIdx.x;
  int stride = gridDim.x * 256;
  for (; i < n4; i += stride) {
    float4 v = *(const float4*)(src + (size_t)i * 4);
    *(uint2*)(dst + (size_t)i * 4) = make_uint2(pack_bf16(v.x, v.y), pack_bf16(v.z, v.w));
  }
}

// ---------------- fp32 [E][R][C] -> bf16 [E][C][R] transpose-convert ----------------
__global__ __launch_bounds__(256) void k_tconv(const float* __restrict__ src,
                                               __hip_bfloat16* __restrict__ dst,
                                               int R, int C) {
  __shared__ unsigned short s[64][88];
  int nrt = R >> 6, nct = C >> 6;
  int bid = blockIdx.x;
  int e  = bid / (nrt * nct);
  int rr = bid % (nrt * nct);
  int rt = rr / nct, ct = rr % nct;
  int r0 = rt * 64, c0 = ct * 64;
  const float* sp = src + (size_t)e * R * C;
  int t = threadIdx.x;
  int lr  = t >> 4;
  int lc4 = (t & 15) * 4;
  #pragma unroll
  for (int p = 0; p < 4; ++p) {
    int r = lr + p * 16;
    float4 v = *(const float4*)(sp + (size_t)(r0 + r) * C + c0 + lc4);
    s[lc4 + 0][r] = bf16_1(v.x);
    s[lc4 + 1][r] = bf16_1(v.y);
    s[lc4 + 2][r] = bf16_1(v.z);
    s[lc4 + 3][r] = bf16_1(v.w);
  }
  __syncthreads();
  __hip_bfloat16* dp = dst + (size_t)e * C * R;
  int wc   = t >> 2;
  int wr16 = (t & 3) * 16;
  uint4 o0 = *(const uint4*)&s[wc][wr16];
  uint4 o1 = *(const uint4*)&s[wc][wr16 + 8];
  __hip_bfloat16* o = dp + (size_t)(c0 + wc) * R + r0 + wr16;
  *(uint4*)o = o0;
  *(uint4*)(o + 8) = o1;
}

// ============ 256x256 grouped GEMMs: dbuf + counted vmcnt + swizzled LDS ============
// LDS layout per buffer: A tile 256 rows x 64 bf16 (128B rows), then B tile same.
// Physical byte within row: c_phys = c_logical ^ ((row&7)<<4). Staging pre-applies the
// inverse permutation on the GLOBAL source column so gl_lds (linear dest) lands swizzled.

// GEMM1: act[e*CAP+m][h] = GEGLU( gather(xb) @ gupT[e]^T ) * prob
__global__ __launch_bounds__(512, 1) void k_gemm1n(
    const __hip_bfloat16* __restrict__ xb, const __hip_bfloat16* __restrict__ gupT,
    const int* __restrict__ counts, const int* __restrict__ tok,
    const float* __restrict__ pb, __hip_bfloat16* __restrict__ act)
{
  const int MT = CAP / 256;        // 4
  const int NT = TWO_INTER / 256;  // 11
  const int nwg = N_EXPERTS * NT * MT;  // 1408, %8==0
  int bid = (int)((blockIdx.x & 7) * (nwg >> 3) + (blockIdx.x >> 3));
  int e  = bid / (NT * MT);
  int rr = bid % (NT * MT);
  int nt = rr / MT, mt = rr % MT;
  const int cnt = counts[e];
  const int m0 = mt * 256;
  if (m0 >= cnt) return;
  const int n0 = nt * 256;

  __shared__ char smem[131072];       // [buf][A 32KB | B 32KB]
  __shared__ int toks[256];

  const int tid = threadIdx.x, lane = tid & 63, w = tid >> 6;  // 8 waves
  const int wr = w >> 2, wc = w & 3;                            // 2M x 4N
  if (tid < 256) toks[tid] = tok[e * CAP + m0 + tid];
  __syncthreads();

  const __hip_bfloat16* gT = gupT + (size_t)e * TWO_INTER * DIM;
  // staging: thread covers (row = i*64 + tid>>3, slot = lane&7); swizzled source column
  const int col8 = (((lane & 7) ^ ((lane >> 3) & 7)) * 8);
  const __hip_bfloat16* ab[4];
  const __hip_bfloat16* bb[4];
  #pragma unroll
  for (int i = 0; i < 4; ++i) {
    int row = i * 64 + (tid >> 3);
    ab[i] = xb + (size_t)toks[row] * DIM + col8;
    bb[i] = gT + (size_t)(n0 + row) * DIM + col8;
  }

  f32x4 acc[8][4];
  #pragma unroll
  for (int i = 0; i < 8; ++i)
    #pragma unroll
    for (int j = 0; j < 4; ++j) acc[i][j] = (f32x4){0.f, 0.f, 0.f, 0.f};

  const int KT = DIM / 64;  // 32

  #define STAGE1(kt, buf) do {                                   \
    const int k0_ = (kt) * 64;                                   \
    char* base_ = smem + (buf) * 65536;                          \
    _Pragma("unroll")                                            \
    for (int i_ = 0; i_ < 4; ++i_) {                             \
      int loff_ = (i_ * 512 + tid) * 16;                         \
      gl_lds16(ab[i_] + k0_, base_ + loff_);                     \
      gl_lds16(bb[i_] + k0_, base_ + 32768 + loff_);             \
    }                                                            \
  } while (0)

  #define COMPUTE1(buf) do {                                     \
    const char* Ab_ = smem + (buf) * 65536;                      \
    const char* Bb_ = Ab_ + 32768;                               \
    _Pragma("unroll")                                            \
    for (int ks_ = 0; ks_ < 2; ++ks_) {                          \
      const int koff_ = (ks_ * 64 + ((lane >> 4) << 4)) ^ ((lane & 7) << 4); \
      short8 af_[8], bf_[4];                                     \
      _Pragma("unroll")                                          \
      for (int mi_ = 0; mi_ < 8; ++mi_)                          \
        af_[mi_] = *(const short8*)(Ab_ + (wr * 128 + mi_ * 16 + (lane & 15)) * 128 + koff_); \
      _Pragma("unroll")                                          \
      for (int ni_ = 0; ni_ < 4; ++ni_)                          \
        bf_[ni_] = *(const short8*)(Bb_ + (wc * 64 + ni_ * 16 + (lane & 15)) * 128 + koff_); \
      _Pragma("unroll")                                          \
      for (int mi_ = 0; mi_ < 8; ++mi_)                          \
        _Pragma("unroll")                                        \
        for (int ni_ = 0; ni_ < 4; ++ni_)                        \
          acc[mi_][ni_] = __builtin_amdgcn_mfma_f32_16x16x32_bf16(af_[mi_], bf_[ni_], acc[mi_][ni_], 0, 0, 0); \
    }                                                            \
  } while (0)

  STAGE1(0, 0);
  for (int kt = 0; kt < KT - 1; ++kt) {
    STAGE1(kt + 1, (kt + 1) & 1);
    asm volatile("s_waitcnt vmcnt(8)" ::: "memory");  // current tile's 8 landed; next 8 in flight
    __builtin_amdgcn_s_barrier();
    __builtin_amdgcn_sched_barrier(0);
    COMPUTE1(kt & 1);
    __builtin_amdgcn_s_barrier();  // all reads of cur done before it is overwritten
  }
  asm volatile("s_waitcnt vmcnt(0)" ::: "memory");
  __builtin_amdgcn_s_barrier();
  __builtin_amdgcn_sched_barrier(0);
  COMPUTE1((KT - 1) & 1);

  const int colp = lane & 15;
  const int rgrp = lane >> 4;
  #pragma unroll
  for (int mi = 0; mi < 8; ++mi) {
    #pragma unroll
    for (int j = 0; j < 4; ++j) {
      int rowl = wr * 128 + mi * 16 + rgrp * 4 + j;
      float prob = pb[e * CAP + m0 + rowl];
      size_t arow = (size_t)(e * CAP + m0 + rowl) * INTER;
      #pragma unroll
      for (int ni = 0; ni < 4; ++ni) {
        float v = acc[mi][ni][j];
        float other = __shfl_xor(v, 1, 64);
        if ((lane & 1) == 0) {
          float gate = fminf(v, 7.0f);
          float up   = fminf(fmaxf(other, -7.0f), 7.0f);
          float glu  = gate / (1.0f + __expf(-1.702f * gate));
          float a    = glu * (up + 1.0f) * prob;
          int nh = n0 + wc * 64 + ni * 16 + colp;
          act[arow + (nh >> 1)] = __float2bfloat16(a);
        }
      }
    }
  }
  #undef STAGE1
  #undef COMPUTE1
}

// GEMM2: out[tok] += act @ downT[e]^T
__global__ __launch_bounds__(512, 1) void k_gemm2n(
    const __hip_bfloat16* __restrict__ act, const __hip_bfloat16* __restrict__ downT,
    const int* __restrict__ counts, const int* __restrict__ tok,
    float* __restrict__ out)
{
  const int MT = CAP / 256;  // 4
  const int NT = DIM / 256;  // 8
  const int nwg = N_EXPERTS * NT * MT;  // 1024
  int bid = (int)((blockIdx.x & 7) * (nwg >> 3) + (blockIdx.x >> 3));
  int e  = bid / (NT * MT);
  int rr = bid % (NT * MT);
  int nt = rr / MT, mt = rr % MT;
  const int cnt = counts[e];
  const int m0 = mt * 256;
  if (m0 >= cnt) return;
  const int n0 = nt * 256;

  __shared__ char smem[131072];
  __shared__ int toks2[256];

  const int tid = threadIdx.x, lane = tid & 63, w = tid >> 6;
  const int wr = w >> 2, wc = w & 3;
  if (tid < 256) toks2[tid] = tok[e * CAP + m0 + tid];
  __syncthreads();

  const __hip_bfloat16* dT = downT + (size_t)e * DIM * INTER;
  const int col8 = (((lane & 7) ^ ((lane >> 3) & 7)) * 8);
  const __hip_bfloat16* ab[4];
  const __hip_bfloat16* bb[4];
  #pragma unroll
  for (int i = 0; i < 4; ++i) {
    int row = i * 64 + (tid >> 3);
    ab[i] = act + (size_t)(e * CAP + m0 + row) * INTER + col8;
    bb[i] = dT + (size_t)(n0 + row) * INTER + col8;
  }

  f32x4 acc[8][4];
  #pragma unroll
  for (int i = 0; i < 8; ++i)
    #pragma unroll
    for (int j = 0; j < 4; ++j) acc[i][j] = (f32x4){0.f, 0.f, 0.f, 0.f};

  const int KT = INTER / 64;  // 22

  #define STAGE2(kt, buf) do {                                   \
    const int k0_ = (kt) * 64;                                   \
    char* base_ = smem + (buf) * 65536;                          \
    _Pragma("unroll")                                            \
    for (int i_ = 0; i_ < 4; ++i_) {                             \
      int loff_ = (i_ * 512 + tid) * 16;                         \
      gl_lds16(ab[i_] + k0_, base_ + loff_);                     \
      gl_lds16(bb[i_] + k0_, base_ + 32768 + loff_);             \
    }                                                            \
  } while (0)

  #define COMPUTE2(buf) do {                                     \
    const char* Ab_ = smem + (buf) * 65536;                      \
    const char* Bb_ = Ab_ + 32768;                               \
    _Pragma("unroll")                                            \
    for (int ks_ = 0; ks_ < 2; ++ks_) {                          \
      const int koff_ = (ks_ * 64 + ((lane >> 4) << 4)) ^ ((lane & 7) << 4); \
      short8 af_[8], bf_[4];                                     \
      _Pragma("unroll")                                          \
      for (int mi_ = 0; mi_ < 8; ++mi_)                          \
        af_[mi_] = *(const short8*)(Ab_ + (wr * 128 + mi_ * 16 + (lane & 15)) * 128 + koff_); \
      _Pragma("unroll")                                          \
      for (int ni_ = 0; ni_ < 4; ++ni_)                          \
        bf_[ni_] = *(const short8*)(Bb_ + (wc * 64 + ni_ * 16 + (lane & 15)) * 128 + koff_); \
      _Pragma("unroll")                                          \
      for (int mi_ = 0; mi_ < 8; ++mi_)                          \
        _Pragma("unroll")                                        \
        for (int ni_ = 0; ni_ < 4; ++ni_)                        \
          acc[mi_][ni_] = __builtin_amdgcn_mfma_f32_16x16x32_bf16(af_[mi_], bf_[ni_], acc[mi_][ni_], 0, 0, 0); \
    }                                                            \
  } while (0)

  STAGE2(0, 0);
  for (int kt = 0; kt < KT - 1; ++kt) {
    STAGE2(kt + 1, (kt + 1) & 1);
    asm volatile("s_waitcnt vmcnt(8)" ::: "memory");
    __builtin_amdgcn_s_barrier();
    __builtin_amdgcn_sched_barrier(0);
    COMPUTE2(kt & 1);
    __builtin_amdgcn_s_barrier();
  }
  asm volatile("s_waitcnt vmcnt(0)" ::: "memory");
  __builtin_amdgcn_s_barrier();
  __builtin_amdgcn_sched_barrier(0);
  COMPUTE2((KT - 1) & 1);

  const int colp = lane & 15;
  const int rgrp = lane >> 4;
  #pragma unroll
  for (int mi = 0; mi < 8; ++mi) {
    #pragma unroll
    for (int j = 0; j < 4; ++j) {
      int rowl = wr * 128 + mi * 16 + rgrp * 4 + j;
      int t = toks2[rowl];
      float* orow = out + (size_t)t * DIM + n0;
      #pragma unroll
      for (int ni = 0; ni < 4; ++ni)
        atomicAdd(orow + wc * 64 + ni * 16 + colp, acc[mi][ni][j]);
    }
  }
  #undef STAGE2
  #undef COMPUTE2
}

// ================= launch =================

extern "C" void kernel_launch(void* const* d_in, const int* in_sizes, int n_in,
                              void* d_out, int out_size, void* d_ws, size_t ws_size,
                              hipStream_t stream) {
  const float* x     = (const float*)d_in[0];
  const int*   tmask = (const int*)d_in[1];
  const float* w     = (const float*)d_in[2];
  const int*   idx   = (const int*)d_in[3];
  const float* gup   = (const float*)d_in[4];
  const float* down  = (const float*)d_in[5];
  float* out = (float*)d_out;

  char* ws = (char*)d_ws;
  const size_t off_tok   = 256;
  const size_t off_pb    = 256 + 131072;
  const size_t off_act   = 256 + 262144;
  const size_t act_bytes = (size_t)N_EXPERTS * CAP * INTER * 2;
  const size_t off_xb    = off_act + act_bytes;
  const size_t xb_bytes  = (size_t)N_TOKENS * DIM * 2;
  const size_t off_gupT  = off_xb + xb_bytes;
  const size_t gupT_b    = (size_t)N_EXPERTS * TWO_INTER * DIM * 2;
  const size_t off_downT = off_gupT + gupT_b;

  int*   counts = (int*)ws;
  int*   tok    = (int*)(ws + off_tok);
  float* pbuf   = (float*)(ws + off_pb);
  __hip_bfloat16* act   = (__hip_bfloat16*)(ws + off_act);
  __hip_bfloat16* xb    = (__hip_bfloat16*)(ws + off_xb);
  __hip_bfloat16* gupT  = (__hip_bfloat16*)(ws + off_gupT);
  __hip_bfloat16* downT = (__hip_bfloat16*)(ws + off_downT);

  hipMemsetAsync(ws, 0, off_act, stream);
  k_build<<<(T_ASSIGN + 255) / 256, 256, 0, stream>>>(tmask, w, idx, counts, tok, pbuf);
  hipMemsetAsync(d_out, 0, (size_t)N_TOKENS * DIM * sizeof(float), stream);

  k_conv<<<2048, 256, 0, stream>>>(x, xb, (N_TOKENS * DIM) / 4);
  k_tconv<<<N_EXPERTS * (DIM / 64) * (TWO_INTER / 64), 256, 0, stream>>>(gup, gupT, DIM, TWO_INTER);
  k_tconv<<<N_EXPERTS * (INTER / 64) * (DIM / 64), 256, 0, stream>>>(down, downT, INTER, DIM);

  k_gemm1n<<<N_EXPERTS * (TWO_INTER / 256) * (CAP / 256), 512, 0, stream>>>(
      xb, gupT, counts, tok, pbuf, act);
  k_gemm2n<<<N_EXPERTS * (DIM / 256) * (CAP / 256), 512, 0, stream>>>(
      act, downT, counts, tok, out);
}

// Round 5
// 1271.307 us; speedup vs baseline: 1.2695x; 1.1102x over previous
//
#include <hip/hip_runtime.h>
#include <hip/hip_bf16.h>
#include <cstdint>
#include <cstddef>

#define N_TOKENS  4096
#define DIM       2048
#define N_EXPERTS 32
#define TOPK      4
#define INTER     1408
#define TWO_INTER 2816
#define CAP       1024
#define T_ASSIGN  (N_TOKENS*TOPK)

typedef __attribute__((ext_vector_type(8))) short short8;
typedef __attribute__((ext_vector_type(4))) float f32x4;

__device__ __forceinline__ unsigned pack_bf16(float a, float b) {
  unsigned ua = __builtin_bit_cast(unsigned, a);
  unsigned ub = __builtin_bit_cast(unsigned, b);
  ua = (ua + 0x8000u) >> 16;
  ub = (ub + 0x8000u) & 0xFFFF0000u;
  return ua | ub;
}
__device__ __forceinline__ unsigned short bf16_1(float a) {
  return (unsigned short)((__builtin_bit_cast(unsigned, a) + 0x8000u) >> 16);
}

__device__ __forceinline__ void gl_lds16(const void* g, void* l) {
  __builtin_amdgcn_global_load_lds(
      (const __attribute__((address_space(1))) unsigned int*)g,
      (__attribute__((address_space(3))) unsigned int*)l, 16, 0, 0);
}

// ---------------- routing build ----------------
__global__ void k_build(const int* __restrict__ tmask, const float* __restrict__ w,
                        const int* __restrict__ idx, int* __restrict__ counts,
                        int* __restrict__ tok, float* __restrict__ pb) {
  int i = blockIdx.x * 256 + threadIdx.x;
  if (i >= T_ASSIGN) return;
  int t = i >> 2;
  int e = idx[i];
  if (e < 0 || e >= N_EXPERTS) return;
  if (tmask[t] == 0) return;
  int r = atomicAdd(&counts[e], 1);
  if (r < CAP) {
    tok[e * CAP + r] = t;
    pb[e * CAP + r] = w[i];
  }
}

// ---------------- fp32 -> bf16 linear convert ----------------
__global__ __launch_bounds__(256) void k_conv(const float* __restrict__ src,
                                              __hip_bfloat16* __restrict__ dst, int n4) {
  int i = blockIdx.x * 256 + threadIdx.x;
  int stride = gridDim.x * 256;
  for (; i < n4; i += stride) {
    float4 v = *(const float4*)(src + (size_t)i * 4);
    *(uint2*)(dst + (size_t)i * 4) = make_uint2(pack_bf16(v.x, v.y), pack_bf16(v.z, v.w));
  }
}

// ---------------- fp32 [E][R][C] -> bf16 [E][C][R] transpose-convert ----------------
__global__ __launch_bounds__(256) void k_tconv(const float* __restrict__ src,
                                               __hip_bfloat16* __restrict__ dst,
                                               int R, int C) {
  __shared__ unsigned short s[64][88];
  int nrt = R >> 6, nct = C >> 6;
  int bid = blockIdx.x;
  int e  = bid / (nrt * nct);
  int rr = bid % (nrt * nct);
  int rt = rr / nct, ct = rr % nct;
  int r0 = rt * 64, c0 = ct * 64;
  const float* sp = src + (size_t)e * R * C;
  int t = threadIdx.x;
  int lr  = t >> 4;
  int lc4 = (t & 15) * 4;
  #pragma unroll
  for (int p = 0; p < 4; ++p) {
    int r = lr + p * 16;
    float4 v = *(const float4*)(sp + (size_t)(r0 + r) * C + c0 + lc4);
    s[lc4 + 0][r] = bf16_1(v.x);
    s[lc4 + 1][r] = bf16_1(v.y);
    s[lc4 + 2][r] = bf16_1(v.z);
    s[lc4 + 3][r] = bf16_1(v.w);
  }
  __syncthreads();
  __hip_bfloat16* dp = dst + (size_t)e * C * R;
  int wc   = t >> 2;
  int wr16 = (t & 3) * 16;
  uint4 o0 = *(const uint4*)&s[wc][wr16];
  uint4 o1 = *(const uint4*)&s[wc][wr16 + 8];
  __hip_bfloat16* o = dp + (size_t)(c0 + wc) * R + r0 + wr16;
  *(uint4*)o = o0;
  *(uint4*)(o + 8) = o1;
}

// ============ persistent 256x256 grouped GEMM core (dbuf, depth-2, swizzled) ============
// LDS per buffer: A 256x64 bf16 (32KB, 128B rows) then B 256x64 (32KB).
// Physical chunk within 128B row: phys = logical ^ (row&7). gl_lds dest linear; the
// inverse permutation is applied to the GLOBAL source column; reads XOR the same.

extern __shared__ char smem_dyn[];

// GEMM1 persistent: act = GEGLU( gather(xb) @ gupT[e]^T ) * prob
__global__ __launch_bounds__(512, 1) void k_gemm1p(
    const __hip_bfloat16* __restrict__ xb, const __hip_bfloat16* __restrict__ gupT,
    const int* __restrict__ counts, const int* __restrict__ tok,
    const float* __restrict__ pb, __hip_bfloat16* __restrict__ act)
{
  __shared__ char smem[131072];
  const int NT = TWO_INTER / 256;  // 11
  const int KT = DIM / 64;         // 32
  const int xcd  = blockIdx.x & 7;
  const int slot = blockIdx.x >> 3;
  const int tid = threadIdx.x, lane = tid & 63, w = tid >> 6;
  const int wr = w >> 2, wc = w & 3;
  const int colsw = (((tid & 7) ^ ((tid >> 3) & 7)) * 8);

  int k = 0;
  for (int ei = 0; ei < 4; ++ei) {
    const int e = xcd * 4 + ei;
    int cc = counts[e]; cc = cc > CAP ? CAP : cc;
    const int mtc = (cc + 255) >> 8;
    for (int nt = 0; nt < NT; ++nt) {
      for (int mt = 0; mt < mtc; ++mt, ++k) {
        if ((k & 31) != slot) continue;
        const int m0 = mt * 256, n0 = nt * 256;
        __syncthreads();  // protect prev item's last-tile LDS reads

        // per-item staging pointers (row = j*64 + tid>>3)
        const __hip_bfloat16* ap[4];
        const __hip_bfloat16* bp[4];
        const __hip_bfloat16* gT = gupT + (size_t)e * TWO_INTER * DIM;
        #pragma unroll
        for (int j = 0; j < 4; ++j) {
          int row = j * 64 + (tid >> 3);
          int tv = tok[e * CAP + m0 + row];
          ap[j] = xb + (size_t)tv * DIM + colsw;
          bp[j] = gT + (size_t)(n0 + row) * DIM + colsw;
        }

        #define STAGE(tt) do {                                         \
          char* base_ = smem + ((tt) & 1) * 65536;                     \
          const int ko_ = (tt) * 64;                                   \
          _Pragma("unroll")                                            \
          for (int j_ = 0; j_ < 4; ++j_) {                             \
            int c_ = (j_ * 512 + tid) * 16;                            \
            gl_lds16(ap[j_] + ko_, base_ + c_);                        \
            gl_lds16(bp[j_] + ko_, base_ + 32768 + c_);                \
          }                                                            \
        } while (0)

        f32x4 acc[8][4];
        #pragma unroll
        for (int i = 0; i < 8; ++i)
          #pragma unroll
          for (int j = 0; j < 4; ++j) acc[i][j] = (f32x4){0.f, 0.f, 0.f, 0.f};

        STAGE(0);
        STAGE(1);
        asm volatile("s_waitcnt vmcnt(8)" ::: "memory");  // tile 0 landed
        __builtin_amdgcn_s_barrier();
        __builtin_amdgcn_sched_barrier(0);

        for (int t = 0; t < KT; ++t) {
          const char* Ab = smem + (t & 1) * 65536;
          const char* Bb = Ab + 32768;
          short8 af[8], bf[4];
          // ---- ks = 0 ----
          {
            const int koff = (((lane >> 4) << 4)) ^ ((lane & 7) << 4);
            #pragma unroll
            for (int mi = 0; mi < 8; ++mi)
              af[mi] = *(const short8*)(Ab + (wr * 128 + mi * 16 + (lane & 15)) * 128 + koff);
            #pragma unroll
            for (int ni = 0; ni < 4; ++ni)
              bf[ni] = *(const short8*)(Bb + (wc * 64 + ni * 16 + (lane & 15)) * 128 + koff);
          }
          __builtin_amdgcn_s_setprio(1);
          #pragma unroll
          for (int mi = 0; mi < 8; ++mi)
            #pragma unroll
            for (int ni = 0; ni < 4; ++ni)
              acc[mi][ni] = __builtin_amdgcn_mfma_f32_16x16x32_bf16(af[mi], bf[ni], acc[mi][ni], 0, 0, 0);
          __builtin_amdgcn_s_setprio(0);
          // ---- ks = 1 reads ----
          short8 af1[8], bf1[4];
          {
            const int koff = (64 + ((lane >> 4) << 4)) ^ ((lane & 7) << 4);
            #pragma unroll
            for (int mi = 0; mi < 8; ++mi)
              af1[mi] = *(const short8*)(Ab + (wr * 128 + mi * 16 + (lane & 15)) * 128 + koff);
            #pragma unroll
            for (int ni = 0; ni < 4; ++ni)
              bf1[ni] = *(const short8*)(Bb + (wc * 64 + ni * 16 + (lane & 15)) * 128 + koff);
          }
          __builtin_amdgcn_sched_barrier(0);
          __builtin_amdgcn_s_barrier();   // all waves' reads of this buffer issued
          if (t + 2 < KT) STAGE(t + 2);   // overwrite this buffer for t+2
          __builtin_amdgcn_s_setprio(1);
          #pragma unroll
          for (int mi = 0; mi < 8; ++mi)
            #pragma unroll
            for (int ni = 0; ni < 4; ++ni)
              acc[mi][ni] = __builtin_amdgcn_mfma_f32_16x16x32_bf16(af1[mi], bf1[ni], acc[mi][ni], 0, 0, 0);
          __builtin_amdgcn_s_setprio(0);
          if (t < KT - 1) {
            if (t == KT - 2) asm volatile("s_waitcnt vmcnt(0)" ::: "memory");
            else             asm volatile("s_waitcnt vmcnt(8)" ::: "memory");
            __builtin_amdgcn_s_barrier();
            __builtin_amdgcn_sched_barrier(0);
          }
        }
        #undef STAGE

        // epilogue: GEGLU * prob -> bf16 act
        const int colp = lane & 15;
        const int rgrp = lane >> 4;
        #pragma unroll
        for (int mi = 0; mi < 8; ++mi) {
          #pragma unroll
          for (int j = 0; j < 4; ++j) {
            int rowl = wr * 128 + mi * 16 + rgrp * 4 + j;
            float prob = pb[e * CAP + m0 + rowl];
            size_t arow = (size_t)(e * CAP + m0 + rowl) * INTER;
            #pragma unroll
            for (int ni = 0; ni < 4; ++ni) {
              float v = acc[mi][ni][j];
              float other = __shfl_xor(v, 1, 64);
              if ((lane & 1) == 0) {
                float gate = fminf(v, 7.0f);
                float up   = fminf(fmaxf(other, -7.0f), 7.0f);
                float glu  = gate / (1.0f + __expf(-1.702f * gate));
                float a    = glu * (up + 1.0f) * prob;
                int nh = n0 + wc * 64 + ni * 16 + colp;
                act[arow + (nh >> 1)] = __float2bfloat16(a);
              }
            }
          }
        }
      }
    }
  }
}

// GEMM2 persistent: out[tok] += act @ downT[e]^T
__global__ __launch_bounds__(512, 1) void k_gemm2p(
    const __hip_bfloat16* __restrict__ act, const __hip_bfloat16* __restrict__ downT,
    const int* __restrict__ counts, const int* __restrict__ tok,
    float* __restrict__ out)
{
  __shared__ char smem[131072];
  const int NT = DIM / 256;    // 8
  const int KT = INTER / 64;   // 22
  const int xcd  = blockIdx.x & 7;
  const int slot = blockIdx.x >> 3;
  const int tid = threadIdx.x, lane = tid & 63, w = tid >> 6;
  const int wr = w >> 2, wc = w & 3;
  const int colsw = (((tid & 7) ^ ((tid >> 3) & 7)) * 8);

  int k = 0;
  for (int ei = 0; ei < 4; ++ei) {
    const int e = xcd * 4 + ei;
    int cc = counts[e]; cc = cc > CAP ? CAP : cc;
    const int mtc = (cc + 255) >> 8;
    for (int nt = 0; nt < NT; ++nt) {
      for (int mt = 0; mt < mtc; ++mt, ++k) {
        if ((k & 31) != slot) continue;
        const int m0 = mt * 256, n0 = nt * 256;
        __syncthreads();

        const __hip_bfloat16* ap[4];
        const __hip_bfloat16* bp[4];
        const __hip_bfloat16* dT = downT + (size_t)e * DIM * INTER;
        #pragma unroll
        for (int j = 0; j < 4; ++j) {
          int row = j * 64 + (tid >> 3);
          ap[j] = act + (size_t)(e * CAP + m0 + row) * INTER + colsw;
          bp[j] = dT + (size_t)(n0 + row) * INTER + colsw;
        }

        #define STAGE(tt) do {                                         \
          char* base_ = smem + ((tt) & 1) * 65536;                     \
          const int ko_ = (tt) * 64;                                   \
          _Pragma("unroll")                                            \
          for (int j_ = 0; j_ < 4; ++j_) {                             \
            int c_ = (j_ * 512 + tid) * 16;                            \
            gl_lds16(ap[j_] + ko_, base_ + c_);                        \
            gl_lds16(bp[j_] + ko_, base_ + 32768 + c_);                \
          }                                                            \
        } while (0)

        f32x4 acc[8][4];
        #pragma unroll
        for (int i = 0; i < 8; ++i)
          #pragma unroll
          for (int j = 0; j < 4; ++j) acc[i][j] = (f32x4){0.f, 0.f, 0.f, 0.f};

        STAGE(0);
        STAGE(1);
        asm volatile("s_waitcnt vmcnt(8)" ::: "memory");
        __builtin_amdgcn_s_barrier();
        __builtin_amdgcn_sched_barrier(0);

        for (int t = 0; t < KT; ++t) {
          const char* Ab = smem + (t & 1) * 65536;
          const char* Bb = Ab + 32768;
          short8 af[8], bf[4];
          {
            const int koff = (((lane >> 4) << 4)) ^ ((lane & 7) << 4);
            #pragma unroll
            for (int mi = 0; mi < 8; ++mi)
              af[mi] = *(const short8*)(Ab + (wr * 128 + mi * 16 + (lane & 15)) * 128 + koff);
            #pragma unroll
            for (int ni = 0; ni < 4; ++ni)
              bf[ni] = *(const short8*)(Bb + (wc * 64 + ni * 16 + (lane & 15)) * 128 + koff);
          }
          __builtin_amdgcn_s_setprio(1);
          #pragma unroll
          for (int mi = 0; mi < 8; ++mi)
            #pragma unroll
            for (int ni = 0; ni < 4; ++ni)
              acc[mi][ni] = __builtin_amdgcn_mfma_f32_16x16x32_bf16(af[mi], bf[ni], acc[mi][ni], 0, 0, 0);
          __builtin_amdgcn_s_setprio(0);
          short8 af1[8], bf1[4];
          {
            const int koff = (64 + ((lane >> 4) << 4)) ^ ((lane & 7) << 4);
            #pragma unroll
            for (int mi = 0; mi < 8; ++mi)
              af1[mi] = *(const short8*)(Ab + (wr * 128 + mi * 16 + (lane & 15)) * 128 + koff);
            #pragma unroll
            for (int ni = 0; ni < 4; ++ni)
              bf1[ni] = *(const short8*)(Bb + (wc * 64 + ni * 16 + (lane & 15)) * 128 + koff);
          }
          __builtin_amdgcn_sched_barrier(0);
          __builtin_amdgcn_s_barrier();
          if (t + 2 < KT) STAGE(t + 2);
          __builtin_amdgcn_s_setprio(1);
          #pragma unroll
          for (int mi = 0; mi < 8; ++mi)
            #pragma unroll
            for (int ni = 0; ni < 4; ++ni)
              acc[mi][ni] = __builtin_amdgcn_mfma_f32_16x16x32_bf16(af1[mi], bf1[ni], acc[mi][ni], 0, 0, 0);
          __builtin_amdgcn_s_setprio(0);
          if (t < KT - 1) {
            if (t == KT - 2) asm volatile("s_waitcnt vmcnt(0)" ::: "memory");
            else             asm volatile("s_waitcnt vmcnt(8)" ::: "memory");
            __builtin_amdgcn_s_barrier();
            __builtin_amdgcn_sched_barrier(0);
          }
        }
        #undef STAGE

        const int colp = lane & 15;
        const int rgrp = lane >> 4;
        #pragma unroll
        for (int mi = 0; mi < 8; ++mi) {
          #pragma unroll
          for (int j = 0; j < 4; ++j) {
            int rowl = wr * 128 + mi * 16 + rgrp * 4 + j;
            int tkn = tok[e * CAP + m0 + rowl];
            float* orow = out + (size_t)tkn * DIM + n0;
            #pragma unroll
            for (int ni = 0; ni < 4; ++ni)
              atomicAdd(orow + wc * 64 + ni * 16 + colp, acc[mi][ni][j]);
          }
        }
      }
    }
  }
}

// ================= launch =================

extern "C" void kernel_launch(void* const* d_in, const int* in_sizes, int n_in,
                              void* d_out, int out_size, void* d_ws, size_t ws_size,
                              hipStream_t stream) {
  const float* x     = (const float*)d_in[0];
  const int*   tmask = (const int*)d_in[1];
  const float* w     = (const float*)d_in[2];
  const int*   idx   = (const int*)d_in[3];
  const float* gup   = (const float*)d_in[4];
  const float* down  = (const float*)d_in[5];
  float* out = (float*)d_out;

  char* ws = (char*)d_ws;
  const size_t off_tok   = 256;
  const size_t off_pb    = 256 + 131072;
  const size_t off_act   = 256 + 262144;
  const size_t act_bytes = (size_t)N_EXPERTS * CAP * INTER * 2;
  const size_t off_xb    = off_act + act_bytes;
  const size_t xb_bytes  = (size_t)N_TOKENS * DIM * 2;
  const size_t off_gupT  = off_xb + xb_bytes;
  const size_t gupT_b    = (size_t)N_EXPERTS * TWO_INTER * DIM * 2;
  const size_t off_downT = off_gupT + gupT_b;

  int*   counts = (int*)ws;
  int*   tok    = (int*)(ws + off_tok);
  float* pbuf   = (float*)(ws + off_pb);
  __hip_bfloat16* act   = (__hip_bfloat16*)(ws + off_act);
  __hip_bfloat16* xb    = (__hip_bfloat16*)(ws + off_xb);
  __hip_bfloat16* gupT  = (__hip_bfloat16*)(ws + off_gupT);
  __hip_bfloat16* downT = (__hip_bfloat16*)(ws + off_downT);

  hipMemsetAsync(ws, 0, off_act, stream);
  k_build<<<(T_ASSIGN + 255) / 256, 256, 0, stream>>>(tmask, w, idx, counts, tok, pbuf);
  hipMemsetAsync(d_out, 0, (size_t)N_TOKENS * DIM * sizeof(float), stream);

  k_conv<<<2048, 256, 0, stream>>>(x, xb, (N_TOKENS * DIM) / 4);
  k_tconv<<<N_EXPERTS * (DIM / 64) * (TWO_INTER / 64), 256, 0, stream>>>(gup, gupT, DIM, TWO_INTER);
  k_tconv<<<N_EXPERTS * (INTER / 64) * (DIM / 64), 256, 0, stream>>>(down, downT, INTER, DIM);

  k_gemm1p<<<256, 512, 0, stream>>>(xb, gupT, counts, tok, pbuf, act);
  k_gemm2p<<<256, 512, 0, stream>>>(act, downT, counts, tok, out);
}